// Round 3
// baseline (421.814 us; speedup 1.0000x reference)
//
#include <hip/hip_runtime.h>
#include <hip/hip_bf16.h>

#define B_ 8
#define C_ 192
#define G_ 256
#define E_ 384
#define R_ 4
#define T_ 8192
#define L_ 3
#define K_ 3

typedef __attribute__((ext_vector_type(4))) float f32x4;
typedef __attribute__((ext_vector_type(8))) short bf16x8;

// tanh-form GELU: max abs err vs erf-form ~1e-3, well under bf16 noise.
static __device__ __forceinline__ float gelu_fast(float x) {
    float x2 = x * x;
    float inner = fmaf(0.044715f * x, x2, x);
    float z2 = 1.5957691216057308f * inner;          // 2*sqrt(2/pi)*inner
    float e = __expf(z2);
    float r = 1.0f / (e + 1.0f);
    float t = fmaf(-2.0f, r, 1.0f);                  // tanh(z)
    float s = 0.5f * x;
    return fmaf(s, t, s);
}

// ---------------- adapter projections: a = g2 @ w.T + bias -------------
__global__ __launch_bounds__(256) void adapter_kernel(
    const float* __restrict__ g2, const float* __restrict__ w,
    const float* __restrict__ bias, float* __restrict__ out, int rows)
{
    int idx = blockIdx.x * 256 + threadIdx.x;
    int total = L_ * rows * B_;
    if (idx >= total) return;
    int bb = idx & 7;
    int lr = idx >> 3;
    int l = lr / rows, rr = lr % rows;
    const float4* wr = (const float4*)(w + (size_t)lr * G_);
    const float4* gb = (const float4*)(g2 + (size_t)bb * G_);
    float s = bias[lr];
    for (int g = 0; g < G_ / 4; ++g) {
        float4 a = gb[g], b = wr[g];
        s = fmaf(a.x, b.x, s); s = fmaf(a.y, b.y, s);
        s = fmaf(a.z, b.z, s); s = fmaf(a.w, b.w, s);
    }
    out[((size_t)l * B_ + bb) * rows + rr] = s;
}

// ---------------- effective weights ------------------------------------
__global__ __launch_bounds__(256) void build_w1_kernel(
    const float* __restrict__ wm, const float* __restrict__ ain,
    const float* __restrict__ aout, __hip_bfloat16* __restrict__ out)
{
    int idx = blockIdx.x * 256 + threadIdx.x;
    if (idx >= L_ * B_ * E_ * C_) return;
    int c = idx % C_;
    int e = (idx / C_) % E_;
    int b = (idx / (C_ * E_)) % B_;
    int l = idx / (C_ * E_ * B_);
    float v = wm[((size_t)l * E_ + e) * C_ + c];
    const float* ai = ain + ((size_t)l * B_ + b) * (C_ * R_);
    const float* ao = aout + ((size_t)l * B_ + b) * (R_ * E_);
#pragma unroll
    for (int r = 0; r < R_; ++r) v = fmaf(ai[c * R_ + r], ao[r * E_ + e], v);
    out[idx] = __float2bfloat16(v);
}

__global__ __launch_bounds__(256) void build_w2_kernel(
    const float* __restrict__ wm, const float* __restrict__ ain,
    const float* __restrict__ aout, __hip_bfloat16* __restrict__ out)
{
    int idx = blockIdx.x * 256 + threadIdx.x;
    if (idx >= L_ * B_ * C_ * E_) return;
    int e = idx % E_;
    int c = (idx / E_) % C_;
    int b = (idx / (C_ * E_)) % B_;
    int l = idx / (C_ * E_ * B_);
    float v = wm[((size_t)l * C_ + c) * E_ + e];
    const float* ai = ain + ((size_t)l * B_ + b) * (E_ * R_);
    const float* ao = aout + ((size_t)l * B_ + b) * (R_ * C_);
#pragma unroll
    for (int r = 0; r < R_; ++r) v = fmaf(ai[e * R_ + r], ao[r * C_ + c], v);
    out[idx] = __float2bfloat16(v);
}

// -------- transpose (B,C,T) f32 -> (B,T,C) bf16, with mask -------------
__global__ __launch_bounds__(256) void transpose_in_kernel(
    const float* __restrict__ x, const float* __restrict__ mask,
    __hip_bfloat16* __restrict__ xw)
{
    __shared__ float tile[64][65];
    int b = blockIdx.z, c0 = blockIdx.y * 64, t0 = blockIdx.x * 64;
    for (int i = threadIdx.x; i < 4096; i += 256) {
        int r = i >> 6, col = i & 63;
        tile[r][col] = x[((size_t)b * C_ + c0 + r) * T_ + t0 + col] *
                       mask[(size_t)b * T_ + t0 + col];
    }
    __syncthreads();
    for (int i = threadIdx.x; i < 4096; i += 256) {
        int r = i >> 6, col = i & 63;
        xw[((size_t)b * T_ + t0 + r) * C_ + c0 + col] =
            __float2bfloat16(tile[col][r]);
    }
}

// -------- transpose (B,T,C) bf16 -> (B,C,T) f32 ------------------------
__global__ __launch_bounds__(256) void transpose_out_kernel(
    const __hip_bfloat16* __restrict__ xw, float* __restrict__ out)
{
    __shared__ float tile[64][65];
    int b = blockIdx.z, c0 = blockIdx.y * 64, t0 = blockIdx.x * 64;
    for (int i = threadIdx.x; i < 4096; i += 256) {
        int r = i >> 6, col = i & 63;
        tile[r][col] =
            __bfloat162float(xw[((size_t)b * T_ + t0 + r) * C_ + c0 + col]);
    }
    __syncthreads();
    for (int i = threadIdx.x; i < 4096; i += 256) {
        int r = i >> 6, col = i & 63;
        out[((size_t)b * C_ + c0 + r) * T_ + t0 + col] = tile[col][r];
    }
}

// ---------------- fully fused layer (bf16 state, E k-split) ------------
// xin/xout: (B,T,C) bf16; W1: (B,E,C) bf16; W2: (B,C,E) bf16
__global__ __launch_bounds__(256, 3) void ffn_fused_kernel(
    const __hip_bfloat16* __restrict__ xin, __hip_bfloat16* __restrict__ xout,
    const float* __restrict__ dw, const float* __restrict__ db,
    const float* __restrict__ gamma, const float* __restrict__ beta,
    const float* __restrict__ mask,
    const __hip_bfloat16* __restrict__ W1, const float* __restrict__ b1,
    const __hip_bfloat16* __restrict__ W2, const float* __restrict__ b2,
    int dil)
{
    __shared__ __hip_bfloat16 Hs[64][C_ + 8];    // 25.0 KB (row stride 400B)
    __shared__ __hip_bfloat16 H1s[64][C_ + 8];   // 25.0 KB (half of E per pass)
    int b = blockIdx.y;
    int t0 = blockIdx.x * 64;
    int tid = threadIdx.x;
    int w = tid >> 6, lane = tid & 63;
    int lhi = lane >> 4, llo = lane & 15;

    // ---- staging: dconv (causal dilated K=3) + LayerNorm + mask -> Hs ----
    {
        float cw0[3], cw1[3], cw2[3], bia[3], ga[3], be[3];
#pragma unroll
        for (int cc = 0; cc < 3; ++cc) {
            int c = cc * 64 + lane;
            cw0[cc] = dw[c * K_ + 0];
            cw1[cc] = dw[c * K_ + 1];
            cw2[cc] = dw[c * K_ + 2];
            bia[cc] = db[c]; ga[cc] = gamma[c]; be[cc] = beta[c];
        }
#pragma unroll
        for (int i = 0; i < 16; ++i) {
            int t = t0 + w * 16 + i;
            const __hip_bfloat16* r0 = xin + ((size_t)b * T_ + t) * C_;
            bool has1 = (t - dil) >= 0;
            bool has2 = (t - 2 * dil) >= 0;
            float v[3];
#pragma unroll
            for (int cc = 0; cc < 3; ++cc) {
                int c = cc * 64 + lane;
                float acc = fmaf(cw0[cc], __bfloat162float(r0[c]), bia[cc]);
                if (has1)
                    acc = fmaf(cw1[cc], __bfloat162float(r0[c - dil * C_]), acc);
                if (has2)
                    acc = fmaf(cw2[cc], __bfloat162float(r0[c - 2 * dil * C_]), acc);
                v[cc] = acc;
            }
            float s = v[0] + v[1] + v[2];
            float sq = fmaf(v[0], v[0], fmaf(v[1], v[1], v[2] * v[2]));
#pragma unroll
            for (int o = 32; o >= 1; o >>= 1) {
                s += __shfl_xor(s, o, 64);
                sq += __shfl_xor(sq, o, 64);
            }
            float mu = s * (1.0f / C_);
            float var = sq * (1.0f / C_) - mu * mu;
            float rs = rsqrtf(var + 1e-5f);
            float m = mask[(size_t)b * T_ + t];
#pragma unroll
            for (int cc = 0; cc < 3; ++cc) {
                int c = cc * 64 + lane;
                Hs[w * 16 + i][c] =
                    __float2bfloat16(fmaf((v[cc] - mu) * rs, ga[cc], be[cc]) * m);
            }
        }
    }
    __syncthreads();

    // acc2 accumulates GEMM2 over both E halves
    f32x4 acc2[3][4];
#pragma unroll
    for (int mf = 0; mf < 3; ++mf)
#pragma unroll
        for (int nf = 0; nf < 4; ++nf) acc2[mf][nf] = (f32x4){0.f, 0.f, 0.f, 0.f};

#pragma unroll
    for (int half = 0; half < 2; ++half) {
        // ---- GEMM1 (half): e in [half*192 + w*48, +48), t 0..63 ----
        f32x4 acc1[3][4];
#pragma unroll
        for (int mf = 0; mf < 3; ++mf)
#pragma unroll
            for (int nf = 0; nf < 4; ++nf) acc1[mf][nf] = (f32x4){0.f, 0.f, 0.f, 0.f};

        {
            const __hip_bfloat16* w1p = W1 + (size_t)b * E_ * C_ +
                ((size_t)(half * 192 + w * 48 + llo)) * C_ + lhi * 8;
#pragma unroll
            for (int kc = 0; kc < 6; ++kc) {
                bf16x8 bfr[4];
#pragma unroll
                for (int nf = 0; nf < 4; ++nf)
                    bfr[nf] = *(const bf16x8*)(&Hs[nf * 16 + llo][kc * 32 + lhi * 8]);
#pragma unroll
                for (int mf = 0; mf < 3; ++mf) {
                    bf16x8 af = *(const bf16x8*)(&w1p[(size_t)mf * 16 * C_ + kc * 32]);
#pragma unroll
                    for (int nf = 0; nf < 4; ++nf)
                        acc1[mf][nf] = __builtin_amdgcn_mfma_f32_16x16x32_bf16(
                            af, bfr[nf], acc1[mf][nf], 0, 0, 0);
                }
            }
        }

        // ---- epilogue1: bias + GELU -> H1s (local e' = e - half*192) ----
#pragma unroll
        for (int mf = 0; mf < 3; ++mf) {
            int e0l = w * 48 + mf * 16 + lhi * 4;
            int e0g = half * 192 + e0l;
            float bb[4];
#pragma unroll
            for (int j = 0; j < 4; ++j) bb[j] = b1[e0g + j];
#pragma unroll
            for (int nf = 0; nf < 4; ++nf) {
                int row = nf * 16 + llo;
                union { __hip_bfloat16 h4[4]; int2 i2; } u;
#pragma unroll
                for (int j = 0; j < 4; ++j)
                    u.h4[j] = __float2bfloat16(gelu_fast(acc1[mf][nf][j] + bb[j]));
                *(int2*)(&H1s[row][e0l]) = u.i2;
            }
        }
        __syncthreads();

        // ---- GEMM2 partial: c in [w*48,+48), k over e' in [0,192) ----
        {
            const __hip_bfloat16* w2p = W2 + (size_t)b * C_ * E_ +
                ((size_t)(w * 48 + llo)) * E_ + half * 192 + lhi * 8;
#pragma unroll
            for (int kc = 0; kc < 6; ++kc) {
                bf16x8 bfr[4];
#pragma unroll
                for (int nf = 0; nf < 4; ++nf)
                    bfr[nf] = *(const bf16x8*)(&H1s[nf * 16 + llo][kc * 32 + lhi * 8]);
#pragma unroll
                for (int mf = 0; mf < 3; ++mf) {
                    bf16x8 af = *(const bf16x8*)(&w2p[(size_t)mf * 16 * E_ + kc * 32]);
#pragma unroll
                    for (int nf = 0; nf < 4; ++nf)
                        acc2[mf][nf] = __builtin_amdgcn_mfma_f32_16x16x32_bf16(
                            af, bfr[nf], acc2[mf][nf], 0, 0, 0);
                }
            }
        }
        if (half == 0) __syncthreads();   // before epilogue1b overwrites H1s
    }

    // ---- epilogue2: + b2 + residual (bf16), write xout (bf16) ----
#pragma unroll
    for (int mf = 0; mf < 3; ++mf) {
        int c0 = w * 48 + mf * 16 + lhi * 4;
        float bb[4];
#pragma unroll
        for (int j = 0; j < 4; ++j) bb[j] = b2[c0 + j];
#pragma unroll
        for (int nf = 0; nf < 4; ++nf) {
            int t = t0 + nf * 16 + llo;
            const __hip_bfloat16* pr = xin + ((size_t)b * T_ + t) * C_ + c0;
            __hip_bfloat16* po = xout + ((size_t)b * T_ + t) * C_ + c0;
            union { __hip_bfloat16 h4[4]; int2 i2; } ui, uo;
            ui.i2 = *(const int2*)pr;
#pragma unroll
            for (int j = 0; j < 4; ++j)
                uo.h4[j] = __float2bfloat16(
                    __bfloat162float(ui.h4[j]) + acc2[mf][nf][j] + bb[j]);
            *(int2*)po = uo.i2;
        }
    }
}

extern "C" void kernel_launch(void* const* d_in, const int* in_sizes, int n_in,
                              void* d_out, int out_size, void* d_ws, size_t ws_size,
                              hipStream_t stream) {
    const float* x        = (const float*)d_in[0];
    const float* x_mask   = (const float*)d_in[1];
    const float* g        = (const float*)d_in[2];
    const float* dconv_w  = (const float*)d_in[3];
    const float* dconv_b  = (const float*)d_in[4];
    const float* ln_gamma = (const float*)d_in[5];
    const float* ln_beta  = (const float*)d_in[6];
    const float* p1_w     = (const float*)d_in[7];
    const float* p1_b     = (const float*)d_in[8];
    const float* p1_ain_w = (const float*)d_in[9];
    const float* p1_ain_b = (const float*)d_in[10];
    const float* p1_aout_w= (const float*)d_in[11];
    const float* p1_aout_b= (const float*)d_in[12];
    const float* p2_w     = (const float*)d_in[13];
    const float* p2_b     = (const float*)d_in[14];
    const float* p2_ain_w = (const float*)d_in[15];
    const float* p2_ain_b = (const float*)d_in[16];
    const float* p2_aout_w= (const float*)d_in[17];
    const float* p2_aout_b= (const float*)d_in[18];

    char* ws = (char*)d_ws;
    size_t off = 0;
    __hip_bfloat16* xwA = (__hip_bfloat16*)(ws + off); off += (size_t)B_ * T_ * C_ * 2;
    __hip_bfloat16* xwB = (__hip_bfloat16*)(ws + off); off += (size_t)B_ * T_ * C_ * 2;
    __hip_bfloat16* W1 = (__hip_bfloat16*)(ws + off);  off += (size_t)L_ * B_ * E_ * C_ * 2;
    __hip_bfloat16* W2 = (__hip_bfloat16*)(ws + off);  off += (size_t)L_ * B_ * C_ * E_ * 2;
    float* A1in  = (float*)(ws + off); off += (size_t)L_ * B_ * C_ * R_ * 4;
    float* A1out = (float*)(ws + off); off += (size_t)L_ * B_ * R_ * E_ * 4;
    float* A2in  = (float*)(ws + off); off += (size_t)L_ * B_ * E_ * R_ * 4;
    float* A2out = (float*)(ws + off); off += (size_t)L_ * B_ * R_ * C_ * 4;

    adapter_kernel<<<(L_ * C_ * R_ * B_ + 255) / 256, 256, 0, stream>>>(g, p1_ain_w, p1_ain_b, A1in, C_ * R_);
    adapter_kernel<<<(L_ * E_ * R_ * B_ + 255) / 256, 256, 0, stream>>>(g, p1_aout_w, p1_aout_b, A1out, E_ * R_);
    adapter_kernel<<<(L_ * E_ * R_ * B_ + 255) / 256, 256, 0, stream>>>(g, p2_ain_w, p2_ain_b, A2in, E_ * R_);
    adapter_kernel<<<(L_ * C_ * R_ * B_ + 255) / 256, 256, 0, stream>>>(g, p2_aout_w, p2_aout_b, A2out, C_ * R_);
    build_w1_kernel<<<(L_ * B_ * E_ * C_ + 255) / 256, 256, 0, stream>>>(p1_w, A1in, A1out, W1);
    build_w2_kernel<<<(L_ * B_ * C_ * E_ + 255) / 256, 256, 0, stream>>>(p2_w, A2in, A2out, W2);

    transpose_in_kernel<<<dim3(T_ / 64, C_ / 64, B_), 256, 0, stream>>>(x, x_mask, xwA);

    const int DILS[3] = {1, 3, 9};
    __hip_bfloat16* bufs[2] = {xwA, xwB};
    for (int l = 0; l < L_; ++l) {
        const __hip_bfloat16* src = bufs[l & 1];
        __hip_bfloat16* dst = bufs[(l & 1) ^ 1];
        ffn_fused_kernel<<<dim3(T_ / 64, B_), 256, 0, stream>>>(
            src, dst,
            dconv_w + l * C_ * K_, dconv_b + l * C_,
            ln_gamma + l * C_, ln_beta + l * C_, x_mask,
            W1 + (size_t)l * B_ * E_ * C_, p1_b + l * E_,
            W2 + (size_t)l * B_ * C_ * E_, p2_b + l * C_, DILS[l]);
    }

    transpose_out_kernel<<<dim3(T_ / 64, C_ / 64, B_), 256, 0, stream>>>(xwB, (float*)d_out);
}

// Round 4
// 256.745 us; speedup vs baseline: 1.6429x; 1.6429x over previous
//
#include <hip/hip_runtime.h>
#include <hip/hip_bf16.h>

#define B_ 8
#define C_ 192
#define G_ 256
#define E_ 384
#define R_ 4
#define T_ 8192
#define L_ 3
#define K_ 3

typedef __attribute__((ext_vector_type(4))) float f32x4;
typedef __attribute__((ext_vector_type(8))) short bf16x8;
typedef __attribute__((ext_vector_type(4))) short bf16x4;

static __device__ __forceinline__ float bf2f(short u) {
    union { float f; unsigned int i; } z;
    z.i = ((unsigned int)(unsigned short)u) << 16;
    return z.f;
}

// tanh-form GELU: max abs err vs erf-form ~1e-3, under bf16 noise.
static __device__ __forceinline__ float gelu_fast(float x) {
    float x2 = x * x;
    float inner = fmaf(0.044715f * x, x2, x);
    float e = __expf(1.5957691216057308f * inner);   // e^{2z}
    float r = 1.0f / (e + 1.0f);
    float t = fmaf(-2.0f, r, 1.0f);                  // tanh(z)
    float s = 0.5f * x;
    return fmaf(s, t, s);
}

// ---------- all 4 adapter projections in one launch --------------------
__global__ __launch_bounds__(256) void adapters_kernel(
    const float* __restrict__ g2,
    const float* __restrict__ w0, const float* __restrict__ bi0, float* __restrict__ o0,
    const float* __restrict__ w1, const float* __restrict__ bi1, float* __restrict__ o1,
    const float* __restrict__ w2, const float* __restrict__ bi2, float* __restrict__ o2,
    const float* __restrict__ w3, const float* __restrict__ bi3, float* __restrict__ o3)
{
    const int N0 = L_ * B_ * (C_ * R_);     // 18432
    const int N1 = L_ * B_ * (E_ * R_);     // 36864
    int idx = blockIdx.x * 256 + threadIdx.x;
    const float* w; const float* bi; float* o; int rows; int li;
    if (idx < N0)                      { w=w0; bi=bi0; o=o0; rows=C_*R_; li=idx; }
    else if ((idx -= N0) < N1)         { w=w1; bi=bi1; o=o1; rows=E_*R_; li=idx; }
    else if ((idx -= N1) < N1)         { w=w2; bi=bi2; o=o2; rows=E_*R_; li=idx; }
    else if ((idx -= N1) < N0)         { w=w3; bi=bi3; o=o3; rows=C_*R_; li=idx; }
    else return;
    int bb = li & 7;
    int lr = li >> 3;
    const float4* wr = (const float4*)(w + (size_t)lr * G_);
    const float4* gb = (const float4*)(g2 + (size_t)bb * G_);
    float s = bi[lr];
#pragma unroll 8
    for (int g = 0; g < G_ / 4; ++g) {
        float4 a = gb[g], b = wr[g];
        s = fmaf(a.x, b.x, s); s = fmaf(a.y, b.y, s);
        s = fmaf(a.z, b.z, s); s = fmaf(a.w, b.w, s);
    }
    o[((size_t)(lr / rows) * B_ + bb) * rows + (lr % rows)] = s;
}

// ---------- W1eff (gamma-folded), W2eff, c1 = W1eff @ beta --------------
__global__ __launch_bounds__(256) void builds_kernel(
    const float* __restrict__ p1w, const float* __restrict__ p2w,
    const float* __restrict__ gam, const float* __restrict__ bet,
    const float* __restrict__ A1in, const float* __restrict__ A1out,
    const float* __restrict__ A2in, const float* __restrict__ A2out,
    __hip_bfloat16* __restrict__ W1, __hip_bfloat16* __restrict__ W2,
    float* __restrict__ C1)
{
    const int W1B = (L_ * B_ * E_ * C_) / 256;   // 6912 blocks
    int blk = blockIdx.x;
    if (blk < W1B) {
        int idx = blk * 256 + threadIdx.x;
        int c = idx % C_;
        int e = (idx / C_) % E_;
        int b = (idx / (C_ * E_)) % B_;
        int l = idx / (C_ * E_ * B_);
        float v = p1w[((size_t)l * E_ + e) * C_ + c];
        const float* ai = A1in + ((size_t)l * B_ + b) * (C_ * R_);
        const float* ao = A1out + ((size_t)l * B_ + b) * (R_ * E_);
#pragma unroll
        for (int r = 0; r < R_; ++r) v = fmaf(ai[c * R_ + r], ao[r * E_ + e], v);
        W1[idx] = __float2bfloat16(v * gam[l * C_ + c]);
    } else if (blk < 2 * W1B) {
        int idx = (blk - W1B) * 256 + threadIdx.x;
        int e = idx % E_;
        int c = (idx / E_) % C_;
        int b = (idx / (C_ * E_)) % B_;
        int l = idx / (C_ * E_ * B_);
        float v = p2w[((size_t)l * C_ + c) * E_ + e];
        const float* ai = A2in + ((size_t)l * B_ + b) * (E_ * R_);
        const float* ao = A2out + ((size_t)l * B_ + b) * (R_ * C_);
#pragma unroll
        for (int r = 0; r < R_; ++r) v = fmaf(ai[e * R_ + r], ao[r * C_ + c], v);
        W2[idx] = __float2bfloat16(v);
    } else {
        int idx = (blk - 2 * W1B) * 256 + threadIdx.x;
        if (idx >= L_ * B_ * E_) return;
        int e = idx % E_;
        int b = (idx / E_) % B_;
        int l = idx / (E_ * B_);
        const float* wrow = p1w + ((size_t)l * E_ + e) * C_;
        const float* ai = A1in + ((size_t)l * B_ + b) * (C_ * R_);
        const float* ao = A1out + ((size_t)l * B_ + b) * (R_ * E_);
        const float* bt = bet + l * C_;
        float s = 0.f;
        for (int c = 0; c < C_; ++c) {
            float v = wrow[c];
#pragma unroll
            for (int r = 0; r < R_; ++r) v = fmaf(ai[c * R_ + r], ao[r * E_ + e], v);
            s = fmaf(v, bt[c], s);
        }
        C1[((size_t)l * B_ + b) * E_ + e] = s;
    }
}

// -------- transpose (B,C,T) f32 -> (B,T,C) bf16, with mask -------------
__global__ __launch_bounds__(256) void transpose_in_kernel(
    const float* __restrict__ x, const float* __restrict__ mask,
    __hip_bfloat16* __restrict__ xw)
{
    __shared__ float tile[64][65];
    int b = blockIdx.z, c0 = blockIdx.y * 64, t0 = blockIdx.x * 64;
#pragma unroll
    for (int it = 0; it < 4; ++it) {
        int i = it * 256 + threadIdx.x;
        int r = i >> 4, cq = i & 15;
        float4 xv = *(const float4*)(&x[((size_t)b * C_ + c0 + r) * T_ + t0 + cq * 4]);
        float4 mv = *(const float4*)(&mask[(size_t)b * T_ + t0 + cq * 4]);
        tile[r][cq * 4 + 0] = xv.x * mv.x;
        tile[r][cq * 4 + 1] = xv.y * mv.y;
        tile[r][cq * 4 + 2] = xv.z * mv.z;
        tile[r][cq * 4 + 3] = xv.w * mv.w;
    }
    __syncthreads();
#pragma unroll
    for (int it = 0; it < 4; ++it) {
        int i = it * 256 + threadIdx.x;
        int r = i >> 4, cq = i & 15;
        union { __hip_bfloat16 h[4]; int2 i2; } u;
#pragma unroll
        for (int j = 0; j < 4; ++j) u.h[j] = __float2bfloat16(tile[cq * 4 + j][r]);
        *(int2*)(&xw[((size_t)b * T_ + t0 + r) * C_ + c0 + cq * 4]) = u.i2;
    }
}

// -------- transpose (B,T,C) bf16 -> (B,C,T) f32 ------------------------
__global__ __launch_bounds__(256) void transpose_out_kernel(
    const __hip_bfloat16* __restrict__ xw, float* __restrict__ out)
{
    __shared__ float tile[64][65];
    int b = blockIdx.z, c0 = blockIdx.y * 64, t0 = blockIdx.x * 64;
#pragma unroll
    for (int it = 0; it < 4; ++it) {
        int i = it * 256 + threadIdx.x;
        int r = i >> 4, cq = i & 15;   // r = t-row, cq = c-quad
        bf16x4 v = *(const bf16x4*)(&xw[((size_t)b * T_ + t0 + r) * C_ + c0 + cq * 4]);
#pragma unroll
        for (int j = 0; j < 4; ++j) tile[cq * 4 + j][r] = bf2f(v[j]);
    }
    __syncthreads();
#pragma unroll
    for (int it = 0; it < 4; ++it) {
        int i = it * 256 + threadIdx.x;
        int r = i >> 4, cq = i & 15;   // r = c-row, cq = t-quad
        float4 o;
        o.x = tile[r][cq * 4 + 0];
        o.y = tile[r][cq * 4 + 1];
        o.z = tile[r][cq * 4 + 2];
        o.w = tile[r][cq * 4 + 3];
        *(float4*)(&out[((size_t)b * C_ + c0 + r) * T_ + t0 + cq * 4]) = o;
    }
}

// ---------------- fused layer: dconv+LN+mask -> GEMM1+GELU -> GEMM2 ----
// xin/xout (B,T,C) bf16 ping-pong. W1: gamma-folded (B,E,C); W2: (B,C,E).
// c1[b][e] = W1eff @ beta (beta term of folded LN affine).
__global__ __launch_bounds__(256, 2) void ffn_fused_kernel(
    const __hip_bfloat16* __restrict__ xin, __hip_bfloat16* __restrict__ xout,
    const float* __restrict__ dw, const float* __restrict__ db,
    const float* __restrict__ mask,
    const __hip_bfloat16* __restrict__ W1, const float* __restrict__ b1,
    const float* __restrict__ c1,
    const __hip_bfloat16* __restrict__ W2, const float* __restrict__ b2,
    int dil)
{
    __shared__ __hip_bfloat16 Hs[64][C_ + 8];    // 25.6 KB
    __shared__ __hip_bfloat16 H1s[64][E_ + 8];   // 50.2 KB
    const int b = blockIdx.y;
    const int t0 = blockIdx.x * 64;
    const int tid = threadIdx.x;
    const int wv = tid >> 6, lane = tid & 63;
    const int llo = lane & 15, lhi = lane >> 4;
    const size_t xbase = (size_t)b * T_ * C_;

    // ---- staging: 16-lane groups, 4 rows each; lane owns 12 channels ----
    {
        const int grp = tid >> 4, gl = tid & 15;
        const int cbase = gl * 12;
        float4 wf[9], dbf[3];
#pragma unroll
        for (int q = 0; q < 9; ++q) wf[q] = *(const float4*)(dw + cbase * 3 + q * 4);
#pragma unroll
        for (int q = 0; q < 3; ++q) dbf[q] = *(const float4*)(db + cbase + q * 4);
#pragma unroll
        for (int rr = 0; rr < 4; ++rr) {
            int tl = grp * 4 + rr;
            int t = t0 + tl;
            float v[12];
#pragma unroll
            for (int j = 0; j < 12; ++j) v[j] = ((const float*)dbf)[j];
#pragma unroll
            for (int k3 = 0; k3 < 3; ++k3) {
                int tt = t - k3 * dil;
                if (tt >= 0) {
                    const __hip_bfloat16* rp = xin + xbase + (size_t)tt * C_ + cbase;
#pragma unroll
                    for (int q = 0; q < 3; ++q) {
                        bf16x4 xv = *(const bf16x4*)(rp + q * 4);
#pragma unroll
                        for (int jj = 0; jj < 4; ++jj) {
                            int j = q * 4 + jj;
                            v[j] = fmaf(((const float*)wf)[j * 3 + k3], bf2f(xv[jj]), v[j]);
                        }
                    }
                }
            }
            float s = 0.f, sq = 0.f;
#pragma unroll
            for (int j = 0; j < 12; ++j) { s += v[j]; sq = fmaf(v[j], v[j], sq); }
#pragma unroll
            for (int o = 1; o <= 8; o <<= 1) {
                s += __shfl_xor(s, o, 64);
                sq += __shfl_xor(sq, o, 64);
            }
            float mu = s * (1.f / C_);
            float var = fmaf(sq, 1.f / C_, -mu * mu);
            float rs = rsqrtf(var + 1e-5f);
            float m = mask[(size_t)b * T_ + t];
            float sc = rs * m;
            float sh = -mu * sc;
            union { __hip_bfloat16 h[12]; int2 i2[3]; } u;
#pragma unroll
            for (int j = 0; j < 12; ++j)
                u.h[j] = __float2bfloat16(fmaf(v[j], sc, sh));
#pragma unroll
            for (int q = 0; q < 3; ++q)
                *(int2*)(&Hs[tl][cbase + q * 4]) = u.i2[q];
        }
    }
    __syncthreads();

    // ---- GEMM1: wave owns e-quarter [wv*96, +96), all 64 t ----
    const __hip_bfloat16* w1p = W1 + (size_t)b * E_ * C_
        + (size_t)(wv * 96 + llo) * C_ + lhi * 8;
    f32x4 acc1[6][4] = {};
#pragma unroll
    for (int kc = 0; kc < 6; ++kc) {
        bf16x8 bfr[4];
#pragma unroll
        for (int nf = 0; nf < 4; ++nf)
            bfr[nf] = *(const bf16x8*)(&Hs[nf * 16 + llo][kc * 32 + lhi * 8]);
#pragma unroll
        for (int mf = 0; mf < 6; ++mf) {
            bf16x8 af = *(const bf16x8*)(w1p + (size_t)mf * 16 * C_ + kc * 32);
#pragma unroll
            for (int nf = 0; nf < 4; ++nf)
                acc1[mf][nf] = __builtin_amdgcn_mfma_f32_16x16x32_bf16(
                    af, bfr[nf], acc1[mf][nf], 0, 0, 0);
        }
    }

    // ---- epilogue1: + b1 + m_t*c1, GELU -> H1s ----
    float mcol[4];
#pragma unroll
    for (int nf = 0; nf < 4; ++nf)
        mcol[nf] = mask[(size_t)b * T_ + t0 + nf * 16 + llo];
#pragma unroll
    for (int mf = 0; mf < 6; ++mf) {
        int e0 = wv * 96 + mf * 16 + lhi * 4;
        float4 b1v = *(const float4*)(b1 + e0);
        float4 c1v = *(const float4*)(c1 + (size_t)b * E_ + e0);
#pragma unroll
        for (int nf = 0; nf < 4; ++nf) {
            union { __hip_bfloat16 h[4]; int2 i2; } u;
#pragma unroll
            for (int j = 0; j < 4; ++j) {
                float xx = acc1[mf][nf][j] + ((const float*)&b1v)[j]
                         + mcol[nf] * ((const float*)&c1v)[j];
                u.h[j] = __float2bfloat16(gelu_fast(xx));
            }
            *(int2*)(&H1s[nf * 16 + llo][e0]) = u.i2;
        }
    }
    __syncthreads();

    // ---- GEMM2: wave owns c-quarter [wv*48, +48), all 64 t ----
    const __hip_bfloat16* w2p = W2 + (size_t)b * C_ * E_
        + (size_t)(wv * 48 + llo) * E_ + lhi * 8;
    f32x4 acc2[3][4] = {};
#pragma unroll
    for (int kc = 0; kc < 12; ++kc) {
        bf16x8 bfr[4];
#pragma unroll
        for (int nf = 0; nf < 4; ++nf)
            bfr[nf] = *(const bf16x8*)(&H1s[nf * 16 + llo][kc * 32 + lhi * 8]);
#pragma unroll
        for (int mf = 0; mf < 3; ++mf) {
            bf16x8 af = *(const bf16x8*)(w2p + (size_t)mf * 16 * E_ + kc * 32);
#pragma unroll
            for (int nf = 0; nf < 4; ++nf)
                acc2[mf][nf] = __builtin_amdgcn_mfma_f32_16x16x32_bf16(
                    af, bfr[nf], acc2[mf][nf], 0, 0, 0);
        }
    }

    // ---- epilogue2: + b2 + residual, write xout (bf16) ----
#pragma unroll
    for (int mf = 0; mf < 3; ++mf) {
        int c0 = wv * 48 + mf * 16 + lhi * 4;
        float4 b2v = *(const float4*)(b2 + c0);
#pragma unroll
        for (int nf = 0; nf < 4; ++nf) {
            int t = t0 + nf * 16 + llo;
            const __hip_bfloat16* pr = xin + xbase + (size_t)t * C_ + c0;
            __hip_bfloat16* po = xout + xbase + (size_t)t * C_ + c0;
            union { __hip_bfloat16 h[4]; int2 i2; } ui, uo;
            ui.i2 = *(const int2*)pr;
#pragma unroll
            for (int j = 0; j < 4; ++j)
                uo.h[j] = __float2bfloat16(
                    bf2f(*(short*)&ui.h[j]) + acc2[mf][nf][j] + ((const float*)&b2v)[j]);
            *(int2*)po = uo.i2;
        }
    }
}

extern "C" void kernel_launch(void* const* d_in, const int* in_sizes, int n_in,
                              void* d_out, int out_size, void* d_ws, size_t ws_size,
                              hipStream_t stream) {
    const float* x        = (const float*)d_in[0];
    const float* x_mask   = (const float*)d_in[1];
    const float* g        = (const float*)d_in[2];
    const float* dconv_w  = (const float*)d_in[3];
    const float* dconv_b  = (const float*)d_in[4];
    const float* ln_gamma = (const float*)d_in[5];
    const float* ln_beta  = (const float*)d_in[6];
    const float* p1_w     = (const float*)d_in[7];
    const float* p1_b     = (const float*)d_in[8];
    const float* p1_ain_w = (const float*)d_in[9];
    const float* p1_ain_b = (const float*)d_in[10];
    const float* p1_aout_w= (const float*)d_in[11];
    const float* p1_aout_b= (const float*)d_in[12];
    const float* p2_w     = (const float*)d_in[13];
    const float* p2_b     = (const float*)d_in[14];
    const float* p2_ain_w = (const float*)d_in[15];
    const float* p2_ain_b = (const float*)d_in[16];
    const float* p2_aout_w= (const float*)d_in[17];
    const float* p2_aout_b= (const float*)d_in[18];

    char* ws = (char*)d_ws;
    size_t off = 0;
    __hip_bfloat16* xwA = (__hip_bfloat16*)(ws + off); off += (size_t)B_ * T_ * C_ * 2;
    __hip_bfloat16* xwB = (__hip_bfloat16*)(ws + off); off += (size_t)B_ * T_ * C_ * 2;
    __hip_bfloat16* W1 = (__hip_bfloat16*)(ws + off);  off += (size_t)L_ * B_ * E_ * C_ * 2;
    __hip_bfloat16* W2 = (__hip_bfloat16*)(ws + off);  off += (size_t)L_ * B_ * C_ * E_ * 2;
    float* C1    = (float*)(ws + off); off += (size_t)L_ * B_ * E_ * 4;
    float* A1in  = (float*)(ws + off); off += (size_t)L_ * B_ * C_ * R_ * 4;
    float* A1out = (float*)(ws + off); off += (size_t)L_ * B_ * R_ * E_ * 4;
    float* A2in  = (float*)(ws + off); off += (size_t)L_ * B_ * E_ * R_ * 4;
    float* A2out = (float*)(ws + off); off += (size_t)L_ * B_ * R_ * C_ * 4;

    {
        int total = L_ * B_ * (2 * C_ * R_ + 2 * E_ * R_);
        adapters_kernel<<<(total + 255) / 256, 256, 0, stream>>>(
            g,
            p1_ain_w, p1_ain_b, A1in,
            p1_aout_w, p1_aout_b, A1out,
            p2_ain_w, p2_ain_b, A2in,
            p2_aout_w, p2_aout_b, A2out);
    }
    {
        int w1blocks = (L_ * B_ * E_ * C_) / 256;
        int c1blocks = (L_ * B_ * E_ + 255) / 256;
        builds_kernel<<<2 * w1blocks + c1blocks, 256, 0, stream>>>(
            p1_w, p2_w, ln_gamma, ln_beta,
            A1in, A1out, A2in, A2out, W1, W2, C1);
    }

    transpose_in_kernel<<<dim3(T_ / 64, C_ / 64, B_), 256, 0, stream>>>(x, x_mask, xwA);

    const int DILS[3] = {1, 3, 9};
    __hip_bfloat16* bufs[2] = {xwA, xwB};
    for (int l = 0; l < L_; ++l) {
        ffn_fused_kernel<<<dim3(T_ / 64, B_), 256, 0, stream>>>(
            bufs[l & 1], bufs[(l & 1) ^ 1],
            dconv_w + l * C_ * K_, dconv_b + l * C_, x_mask,
            W1 + (size_t)l * B_ * E_ * C_, p1_b + l * E_,
            C1 + (size_t)l * B_ * E_,
            W2 + (size_t)l * B_ * C_ * E_, p2_b + l * C_, DILS[l]);
    }

    transpose_out_kernel<<<dim3(T_ / 64, C_ / 64, B_), 256, 0, stream>>>(xwB, (float*)d_out);
}